// Round 1
// baseline (2674.888 us; speedup 1.0000x reference)
//
#include <hip/hip_runtime.h>
#include <hip/hip_bf16.h>

// ---------------------------------------------------------------------------
// y = relu((x - pb) @ W + be); thr = 128th largest per row; out = y*(y>=thr).
// M=16384, K=4096, N=4096, fp32 in/out.
//
// R5: GEMM ported to the verified 256^2 / BK=64 / 8-wave "8-phase" schedule
// (counted vmcnt, never 0 in main loop; full (row&7) XOR LDS swizzle; setprio
// around MFMA clusters; bijective XCD block swizzle). The 3-product split
// (AhiBhi + AloBhi + AhiBlo) is expressed as one bf16 GEMM with K_eff=12288
// via per-K-tile plane-pointer selection. Top-k stays f64-exact (R2 proven).
// ---------------------------------------------------------------------------

typedef __bf16  bf16x8 __attribute__((ext_vector_type(8)));
typedef float   f32x4  __attribute__((ext_vector_type(4)));

__device__ __forceinline__ unsigned short f2bf(float f) {
    __hip_bfloat16 h = __float2bfloat16(f);
    return __builtin_bit_cast(unsigned short, h);
}
__device__ __forceinline__ float bf2f(unsigned short u) {
    __hip_bfloat16 h = __builtin_bit_cast(__hip_bfloat16, u);
    return __bfloat162float(h);
}

#define GLL16(g, l)                                                          \
    __builtin_amdgcn_global_load_lds(                                        \
        (const __attribute__((address_space(1))) unsigned int*)(g),          \
        (__attribute__((address_space(3))) unsigned int*)(l), 16, 0, 0)

// ---------------------------------------------------------------------------
// x [m][k] fp32 -> Xhi/Xlo [m][k] bf16 (pb folded in). Memory-bound.
// ---------------------------------------------------------------------------
__global__ __launch_bounds__(256)
void presplit_x(const float* __restrict__ x, const float* __restrict__ pb,
                unsigned short* __restrict__ Xhi, unsigned short* __restrict__ Xlo,
                int Kdim, size_t total) {
    size_t base = ((size_t)blockIdx.x * 256 + threadIdx.x) * 8;
    if (base >= total) return;
    int kcol = (int)(base % Kdim);
    __align__(16) unsigned short hi[8], lo[8];
    #pragma unroll
    for (int q = 0; q < 2; ++q) {
        float4 xv = *(const float4*)&x[base + q * 4];
        float4 pv = *(const float4*)&pb[kcol + q * 4];
        float v[4] = {xv.x - pv.x, xv.y - pv.y, xv.z - pv.z, xv.w - pv.w};
        #pragma unroll
        for (int r = 0; r < 4; ++r) {
            hi[q*4+r] = f2bf(v[r]);
            lo[q*4+r] = f2bf(v[r] - bf2f(hi[q*4+r]));
        }
    }
    *(uint4*)&Xhi[base] = *(uint4*)&hi[0];
    *(uint4*)&Xlo[base] = *(uint4*)&lo[0];
}

// ---------------------------------------------------------------------------
// W [k][n] fp32 -> Wt_hi/Wt_lo [n][k] bf16 (transpose + split).
// ---------------------------------------------------------------------------
__global__ __launch_bounds__(256)
void split_transpose_W(const float* __restrict__ W,
                       unsigned short* __restrict__ Wt_hi,
                       unsigned short* __restrict__ Wt_lo,
                       int N, int Kdim) {
    __shared__ float tile[64][65];
    const int tx = threadIdx.x;
    const int nB = blockIdx.x * 64;
    const int kB = blockIdx.y * 64;

    #pragma unroll
    for (int p = 0; p < 4; ++p) {
        int e  = tx + 256 * p;
        int kl = e >> 4;
        int n4 = (e & 15) << 2;
        float4 v = *(const float4*)&W[(size_t)(kB + kl) * N + nB + n4];
        tile[kl][n4 + 0] = v.x; tile[kl][n4 + 1] = v.y;
        tile[kl][n4 + 2] = v.z; tile[kl][n4 + 3] = v.w;
    }
    __syncthreads();

    #pragma unroll
    for (int p = 0; p < 4; ++p) {
        int e  = tx + 256 * p;
        int nl = e >> 4;
        int k4 = (e & 15) << 2;
        unsigned short hi[4], lo[4];
        #pragma unroll
        for (int r = 0; r < 4; ++r) {
            float f = tile[k4 + r][nl];
            hi[r] = f2bf(f);
            lo[r] = f2bf(f - bf2f(hi[r]));
        }
        size_t off = (size_t)(nB + nl) * Kdim + kB + k4;
        *(ushort4*)&Wt_hi[off] = *(ushort4*)&hi[0];
        *(ushort4*)&Wt_lo[off] = *(ushort4*)&lo[0];
    }
}

// ---------------------------------------------------------------------------
// 8-phase 256x256 GEMM, BK=64, 8 waves (2Mx4N), 128 KiB LDS double-buffered.
// K_eff = 3*Kdim: pass0=(Xhi,Whi), pass1=(Xlo,Whi), pass2=(Xhi,Wlo).
// LDS swizzle: 16B chunk_phys = chunk_logical ^ (row&7) -> fragment
// ds_read_b128 is 2-way aliased (free). global_load_lds dest stays linear;
// the per-lane GLOBAL source address is inverse-swizzled (rule #21).
// Counted vmcnt schedule (per-wave, 2 loads/phase, 8/tile):
//   issue order per tile t (for tile t+1): B r0,r1 | B r2,r3 | A r0,r1 | A r2,r3
//   A round r == quadrant-r rows [32r,32r+32) u [128+32r,128+32r+32),
//   consumed at phase r of tile t+1 -> waits {4,5,6,3} never drain in-loop.
// ---------------------------------------------------------------------------
__global__ __launch_bounds__(512, 2)
void gemm_presplit8(const unsigned short* __restrict__ Xhi,
                    const unsigned short* __restrict__ Xlo,
                    const unsigned short* __restrict__ Wt_hi,
                    const unsigned short* __restrict__ Wt_lo,
                    const float* __restrict__ be,
                    float* __restrict__ out, int M, int N, int Kdim) {
    __shared__ unsigned short sA[2][256 * 64];
    __shared__ unsigned short sB[2][256 * 64];

    const int tx   = threadIdx.x;
    const int lane = tx & 63;
    const int wv   = tx >> 6;          // 0..7
    const int ln   = lane & 15;
    const int quad = lane >> 4;
    const int wm   = wv >> 2;          // 0..1 (M half)
    const int wn   = wv & 3;           // 0..3 (N quarter)

    // bijective XCD-aware swizzle (m204): each XCD gets a contiguous chunk;
    // within a chunk, mTile-major so an XCD reuses 2 B-panels across 64 A-rows.
    const int mT = M >> 8, nT = N >> 8, total = mT * nT;
    int wgid = blockIdx.y * gridDim.x + blockIdx.x;
    int xcd = wgid & 7, idx = wgid >> 3;
    int qq = total >> 3, rr = total & 7;
    int swz = (xcd < rr ? xcd * (qq + 1) : rr * (qq + 1) + (xcd - rr) * qq) + idx;
    const int mBase = (swz % mT) << 8;
    const int nBase = (swz / mT) << 8;

    const int lr = tx >> 3;            // 0..63: staged row-within-round
    const int lc = tx & 7;             // physical 16B chunk within row

    // dest chunk = row*8 + lc  (linear: wave-uniform base + lane*16)
    // source logical chunk = lc ^ (row&7)
#define STAGE_B8(bufp, r, srcbase, kcol) do {                                 \
        int row_ = ((r) << 6) + lr;                                           \
        GLL16((srcbase) + (size_t)(nBase + row_) * Kdim + (kcol)              \
                        + ((lc ^ (lr & 7)) << 3),                             \
              &sB[bufp][(row_ << 6) + (lc << 3)]);                            \
    } while (0)
#define STAGE_A8(bufp, r, srcbase, kcol) do {                                 \
        int row_ = (lr < 32) ? (((r) << 5) + lr) : (96 + ((r) << 5) + lr);    \
        GLL16((srcbase) + (size_t)(mBase + row_) * Kdim + (kcol)              \
                        + ((lc ^ (lr & 7)) << 3),                             \
              &sA[bufp][(row_ << 6) + (lc << 3)]);                            \
    } while (0)
    // fragment read: logical chunk = ks*4+quad, physical = ^(row&7)
#define LDA8(bufp, ra, ks) (*(const bf16x8*)&sA[bufp][((ra) << 6) +           \
        (((((ks) << 2) + quad) ^ ((ra) & 7)) << 3)])
#define LDB8(bufp, rb, ks) (*(const bf16x8*)&sB[bufp][((rb) << 6) +           \
        (((((ks) << 2) + quad) ^ ((rb) & 7)) << 3)])

    f32x4 acc[8][4] = {};

    const int KT = Kdim >> 6;          // K-tiles per pass
    const int NT = 3 * KT;             // total K-tiles (3 product passes)

    // prologue: tile 0 = (Xhi, Wt_hi, k=0) into buf 0
    STAGE_B8(0, 0, Wt_hi, 0); STAGE_B8(0, 1, Wt_hi, 0);
    STAGE_B8(0, 2, Wt_hi, 0); STAGE_B8(0, 3, Wt_hi, 0);
    STAGE_A8(0, 0, Xhi, 0);   STAGE_A8(0, 1, Xhi, 0);
    STAGE_A8(0, 2, Xhi, 0);   STAGE_A8(0, 3, Xhi, 0);
    asm volatile("s_waitcnt vmcnt(0)" ::: "memory");
    __builtin_amdgcn_s_barrier();
    __builtin_amdgcn_sched_barrier(0);

    for (int t = 0; t < NT; ++t) {
        const int cur = t & 1, nxt = cur ^ 1;
        const bool more = (t + 1 < NT);
        const unsigned short* An = Xhi;
        const unsigned short* Bn = Wt_hi;
        int k1 = 0;
        if (more) {                      // plane select for tile t+1 (uniform)
            int kk1 = (t + 1) << 6;
            int K2  = Kdim << 1;
            if (kk1 < Kdim)     { An = Xhi; Bn = Wt_hi; k1 = kk1; }
            else if (kk1 < K2)  { An = Xlo; Bn = Wt_hi; k1 = kk1 - Kdim; }
            else                { An = Xhi; Bn = Wt_lo; k1 = kk1 - K2; }
        }

        bf16x8 bv[4][2];                 // B frags read once per tile, held
        #pragma unroll
        for (int q = 0; q < 4; ++q) {
            bf16x8 av[2][2];
            if (q == 0) {
                #pragma unroll
                for (int j = 0; j < 4; ++j)
                    #pragma unroll
                    for (int ks = 0; ks < 2; ++ks)
                        bv[j][ks] = LDB8(cur, wn * 64 + j * 16 + ln, ks);
            }
            #pragma unroll
            for (int ii = 0; ii < 2; ++ii)
                #pragma unroll
                for (int ks = 0; ks < 2; ++ks)
                    av[ii][ks] = LDA8(cur, wm * 128 + (2 * q + ii) * 16 + ln, ks);

            if (more) {                  // stage 2 rounds of tile t+1
                if (q == 0)      { STAGE_B8(nxt, 0, Bn, k1); STAGE_B8(nxt, 1, Bn, k1); }
                else if (q == 1) { STAGE_B8(nxt, 2, Bn, k1); STAGE_B8(nxt, 3, Bn, k1); }
                else if (q == 2) { STAGE_A8(nxt, 0, An, k1); STAGE_A8(nxt, 1, An, k1); }
                else             { STAGE_A8(nxt, 2, An, k1); STAGE_A8(nxt, 3, An, k1); }
            }

            __builtin_amdgcn_s_barrier();
            __builtin_amdgcn_s_setprio(1);
            #pragma unroll
            for (int ks = 0; ks < 2; ++ks)
                #pragma unroll
                for (int ii = 0; ii < 2; ++ii)
                    #pragma unroll
                    for (int j = 0; j < 4; ++j)
                        acc[2 * q + ii][j] = __builtin_amdgcn_mfma_f32_16x16x32_bf16(
                            av[ii][ks], bv[j][ks], acc[2 * q + ii][j], 0, 0, 0);
            __builtin_amdgcn_s_setprio(0);

            // counted waits guarding NEXT phase's ds_reads; published by barrier
            if (q == 0) {
                if (more) asm volatile("s_waitcnt vmcnt(4)" ::: "memory");
                else      asm volatile("s_waitcnt vmcnt(2)" ::: "memory");
            } else if (q == 1) {
                if (more) asm volatile("s_waitcnt vmcnt(5)" ::: "memory");
                else      asm volatile("s_waitcnt vmcnt(1)" ::: "memory");
            } else if (q == 2) {
                if (more) asm volatile("s_waitcnt vmcnt(6)" ::: "memory");
                else      asm volatile("s_waitcnt vmcnt(0)" ::: "memory");
            } else {
                if (more) asm volatile("s_waitcnt vmcnt(3)" ::: "memory");
            }
            __builtin_amdgcn_s_barrier();
            __builtin_amdgcn_sched_barrier(0);
        }
    }

    // epilogue: + b_enc, relu, store (C/D: col=lane&15, row=quad*4+reg)
    #pragma unroll
    for (int j = 0; j < 4; ++j) {
        int n = nBase + wn * 64 + j * 16 + ln;
        float bev = be[n];
        #pragma unroll
        for (int i = 0; i < 8; ++i) {
            #pragma unroll
            for (int r = 0; r < 4; ++r) {
                int m = mBase + wm * 128 + i * 16 + quad * 4 + r;
                out[(size_t)m * N + n] = fmaxf(acc[i][j][r] + bev, 0.f);
            }
        }
    }
#undef STAGE_B8
#undef STAGE_A8
#undef LDA8
#undef LDB8
}

// ---------------------------------------------------------------------------
// R3 fallback GEMM (on-the-fly A split) — used only if ws can't hold X planes
// or the shape isn't 256/64-divisible.
// ---------------------------------------------------------------------------
__global__ __launch_bounds__(256)
void gemm_split_bf16(const float* __restrict__ x, const float* __restrict__ pb,
                     const unsigned short* __restrict__ Wt_hi,
                     const unsigned short* __restrict__ Wt_lo,
                     const float* __restrict__ be,
                     float* __restrict__ out, int M, int N, int Kdim) {
    __shared__ unsigned short sAhi[128][32];
    __shared__ unsigned short sAlo[128][32];
    __shared__ unsigned short sBhi[128][32];
    __shared__ unsigned short sBlo[128][32];

    const int tx    = threadIdx.x;
    const int nBase = blockIdx.x * 128;
    const int mBase = blockIdx.y * 128;
    const int wv    = tx >> 6;
    const int lane  = tx & 63;
    const int ln    = lane & 15;
    const int quad  = lane >> 4;
    const int wm    = wv >> 1;
    const int wn    = wv & 1;
    const int am = tx >> 1;
    const int ak = (tx & 1) * 16;
    const int bn  = wv * 16 + (lane >> 2);
    const int bk8 = (lane & 3) * 8;

    f32x4 acc[4][4] = {};

    for (int k0 = 0; k0 < Kdim; k0 += 32) {
        __syncthreads();
        #pragma unroll
        for (int r = 0; r < 2; ++r) {
            int nrow = r * 64 + bn;
            size_t goff = (size_t)(nBase + nrow) * Kdim + k0 + bk8;
            GLL16(&Wt_hi[goff], &sBhi[nrow][bk8]);
            GLL16(&Wt_lo[goff], &sBlo[nrow][bk8]);
        }
        {
            const float* xrow = x  + (size_t)(mBase + am) * Kdim + k0 + ak;
            const float* pbp  = pb + k0 + ak;
            float v[16];
            #pragma unroll
            for (int q = 0; q < 4; ++q) {
                float4 xv = *(const float4*)(xrow + q * 4);
                float4 pv = *(const float4*)(pbp + q * 4);
                v[q*4+0] = xv.x - pv.x; v[q*4+1] = xv.y - pv.y;
                v[q*4+2] = xv.z - pv.z; v[q*4+3] = xv.w - pv.w;
            }
            __align__(16) unsigned short hi[16], lo[16];
            #pragma unroll
            for (int q = 0; q < 16; ++q) {
                hi[q] = f2bf(v[q]);
                lo[q] = f2bf(v[q] - bf2f(hi[q]));
            }
            *(uint4*)&sAhi[am][ak]     = *(uint4*)&hi[0];
            *(uint4*)&sAhi[am][ak + 8] = *(uint4*)&hi[8];
            *(uint4*)&sAlo[am][ak]     = *(uint4*)&lo[0];
            *(uint4*)&sAlo[am][ak + 8] = *(uint4*)&lo[8];
        }
        __syncthreads();

        bf16x8 ahi[4], alo[4], bhi[4], blo[4];
        #pragma unroll
        for (int i = 0; i < 4; ++i) {
            int m = wm * 64 + i * 16 + ln;
            ahi[i] = *(const bf16x8*)&sAhi[m][quad * 8];
            alo[i] = *(const bf16x8*)&sAlo[m][quad * 8];
        }
        #pragma unroll
        for (int j = 0; j < 4; ++j) {
            int n = wn * 64 + j * 16 + ln;
            bhi[j] = *(const bf16x8*)&sBhi[n][quad * 8];
            blo[j] = *(const bf16x8*)&sBlo[n][quad * 8];
        }
        #pragma unroll
        for (int i = 0; i < 4; ++i)
            #pragma unroll
            for (int j = 0; j < 4; ++j) {
                acc[i][j] = __builtin_amdgcn_mfma_f32_16x16x32_bf16(ahi[i], bhi[j], acc[i][j], 0, 0, 0);
                acc[i][j] = __builtin_amdgcn_mfma_f32_16x16x32_bf16(ahi[i], blo[j], acc[i][j], 0, 0, 0);
                acc[i][j] = __builtin_amdgcn_mfma_f32_16x16x32_bf16(alo[i], bhi[j], acc[i][j], 0, 0, 0);
            }
    }

    #pragma unroll
    for (int j = 0; j < 4; ++j) {
        int n = nBase + wn * 64 + j * 16 + ln;
        float bev = be[n];
        #pragma unroll
        for (int i = 0; i < 4; ++i)
            #pragma unroll
            for (int r = 0; r < 4; ++r) {
                int m = mBase + wm * 64 + i * 16 + quad * 4 + r;
                out[(size_t)m * N + n] = fmaxf(acc[i][j][r] + bev, 0.f);
            }
    }
}

// ---------------------------------------------------------------------------
// Top-k mask with f64-exact boundary decisions (R2, proven).
// ---------------------------------------------------------------------------
#define BAND    2e-4f
#define AMB_CAP 64

__global__ __launch_bounds__(256)
void topk_mask_exact(const float* __restrict__ x, const float* __restrict__ pb,
                     const float* __restrict__ W, const float* __restrict__ be,
                     float* __restrict__ out, int N, int Kdim, int Ksel) {
    __shared__ float    vals[4096];
    __shared__ unsigned hist[256];
    __shared__ unsigned s_prefix;
    __shared__ int      s_k, s_done;
    __shared__ int      s_nhi, s_namb;
    __shared__ int      amb_idx[AMB_CAP];
    __shared__ double   amb_d[AMB_CAP];
    __shared__ int      amb_keep[AMB_CAP];
    __shared__ double   red[4];

    const int tx  = threadIdx.x;
    const int row = blockIdx.x;
    float* rowp = out + (size_t)row * N;

    #pragma unroll
    for (int p = 0; p < 4; ++p) {
        int i = (tx + 256 * p) << 2;
        *(float4*)&vals[i] = *(const float4*)&rowp[i];
    }
    if (tx == 0) { s_done = 0; s_nhi = 0; s_namb = 0; }
    __syncthreads();

    unsigned prefix = 0, prefix_mask = 0;
    int kneed_r = Ksel;
    for (int shift = 24; shift >= 0; shift -= 8) {
        hist[tx] = 0;
        __syncthreads();
        #pragma unroll
        for (int p = 0; p < 16; ++p) {
            unsigned u = __float_as_uint(vals[tx + 256 * p]);
            if (u != 0u && (u & prefix_mask) == prefix)
                atomicAdd(&hist[(u >> shift) & 255u], 1u);
        }
        __syncthreads();
        if (tx == 0) {
            int cum = 0, b;
            for (b = 255; b >= 0; --b) { cum += (int)hist[b]; if (cum >= kneed_r) break; }
            if (b < 0) s_done = 1;
            else { s_prefix = prefix | ((unsigned)b << shift); s_k = kneed_r - (cum - (int)hist[b]); }
        }
        __syncthreads();
        if (s_done) { prefix = 0; break; }
        prefix = s_prefix;
        kneed_r = s_k;
        prefix_mask |= (0xFFu << shift);
        __syncthreads();
    }
    const float thr = __uint_as_float(prefix);

    if (thr < 0.01f) {
        #pragma unroll
        for (int p = 0; p < 4; ++p) {
            int i = (tx + 256 * p) << 2;
            float4 v = *(float4*)&vals[i];
            v.x = (v.x >= thr) ? v.x : 0.f;
            v.y = (v.y >= thr) ? v.y : 0.f;
            v.z = (v.z >= thr) ? v.z : 0.f;
            v.w = (v.w >= thr) ? v.w : 0.f;
            *(float4*)&rowp[i] = v;
        }
        return;
    }

    int my_hi = 0;
    #pragma unroll
    for (int p = 0; p < 16; ++p) {
        float v = vals[tx + 256 * p];
        if (v > thr + BAND) my_hi++;
        else if (v >= thr - BAND) {
            int slot = atomicAdd(&s_namb, 1);
            if (slot < AMB_CAP) amb_idx[slot] = tx + 256 * p;
        }
    }
    atomicAdd(&s_nhi, my_hi);
    __syncthreads();

    const int nhi   = s_nhi;
    const int namb  = (s_namb < AMB_CAP) ? s_namb : AMB_CAP;
    const int kneed = Ksel - nhi;
    const bool fallback = (s_namb > AMB_CAP) || (kneed < 0) || (kneed > s_namb);

    if (fallback) {
        #pragma unroll
        for (int p = 0; p < 16; ++p) {
            int i = tx + 256 * p;
            float v = vals[i];
            rowp[i] = (v >= thr) ? v : 0.f;
        }
        return;
    }

    if (namb > kneed) {
        for (int j = 0; j < namb; ++j) {
            const int n = amb_idx[j];
            double partial = 0.0;
            for (int p = 0; p < Kdim / 256; ++p) {
                int k = tx + 256 * p;
                partial += ((double)x[(size_t)row * Kdim + k] - (double)pb[k]) *
                           (double)W[(size_t)k * N + n];
            }
            #pragma unroll
            for (int off = 32; off > 0; off >>= 1) partial += __shfl_down(partial, off);
            if ((tx & 63) == 0) red[tx >> 6] = partial;
            __syncthreads();
            if (tx == 0) amb_d[j] = red[0] + red[1] + red[2] + red[3] + (double)be[n];
            __syncthreads();
        }
        if (tx == 0) {
            for (int j = 0; j < namb; ++j) {
                int greater = 0;
                for (int l = 0; l < namb; ++l)
                    if (amb_d[l] > amb_d[j]) greater++;
                amb_keep[j] = (greater < kneed) ? 1 : 0;
            }
        }
        __syncthreads();
    } else {
        for (int j = tx; j < namb; j += 256) amb_keep[j] = 1;
        __syncthreads();
    }

    #pragma unroll
    for (int p = 0; p < 16; ++p) {
        int i = tx + 256 * p;
        float v = vals[i];
        float o;
        if (v > thr + BAND) o = v;
        else if (v < thr - BAND) o = 0.f;
        else {
            int keep = 0;
            for (int j = 0; j < namb; ++j)
                if (amb_idx[j] == i) { keep = amb_keep[j]; break; }
            o = keep ? v : 0.f;
        }
        rowp[i] = o;
    }
}

extern "C" void kernel_launch(void* const* d_in, const int* in_sizes, int n_in,
                              void* d_out, int out_size, void* d_ws, size_t ws_size,
                              hipStream_t stream) {
    const float* x  = (const float*)d_in[0];
    const float* pb = (const float*)d_in[1];
    const float* W  = (const float*)d_in[2];
    const float* be = (const float*)d_in[3];
    float* out = (float*)d_out;

    const int D = in_sizes[1];          // 4096
    const int N = in_sizes[3];          // 4096
    const int M = in_sizes[0] / D;      // 16384

    const size_t szW = (size_t)N * D;   // elements per W plane
    const size_t szX = (size_t)M * D;   // elements per X plane
    const size_t needW    = 2ull * szW * sizeof(unsigned short);            // 64 MB
    const size_t needFull = needW + 2ull * szX * sizeof(unsigned short);    // 332 MB

    const bool div256 = (M % 256 == 0) && (N % 256 == 0) && (D % 64 == 0);

    if (ws_size >= needFull && div256) {
        unsigned short* Wt_hi = (unsigned short*)d_ws;
        unsigned short* Wt_lo = Wt_hi + szW;
        unsigned short* Xhi   = Wt_lo + szW;
        unsigned short* Xlo   = Xhi + szX;
        split_transpose_W<<<dim3(N / 64, D / 64), 256, 0, stream>>>(W, Wt_hi, Wt_lo, N, D);
        {
            size_t total = szX;
            int blocks = (int)((total / 8 + 255) / 256);
            presplit_x<<<blocks, 256, 0, stream>>>(x, pb, Xhi, Xlo, D, total);
        }
        gemm_presplit8<<<dim3(N / 256, M / 256), 512, 0, stream>>>(
            Xhi, Xlo, Wt_hi, Wt_lo, be, out, M, N, D);
    } else {
        unsigned short* Wt_hi = (unsigned short*)d_ws;
        unsigned short* Wt_lo = Wt_hi + szW;
        split_transpose_W<<<dim3(N / 64, D / 64), 256, 0, stream>>>(W, Wt_hi, Wt_lo, N, D);
        gemm_split_bf16<<<dim3(N / 128, M / 128), 256, 0, stream>>>(
            x, pb, Wt_hi, Wt_lo, be, out, M, N, D);
    }
    topk_mask_exact<<<M, 256, 0, stream>>>(x, pb, W, be, out, N, D, 128);
}

// Round 2
// 2279.520 us; speedup vs baseline: 1.1734x; 1.1734x over previous
//
#include <hip/hip_runtime.h>
#include <hip/hip_bf16.h>

// ---------------------------------------------------------------------------
// y = relu((x - pb) @ W + be); thr = 128th largest per row; out = y*(y>=thr).
// M=16384, K=4096, N=4096, fp32 in/out.
//
// R6: 256^2 / BK=32 GEMM with ALL FOUR bf16 planes (Ahi,Alo,Bhi,Blo) staged
// once per K-tile (double-buffered, 128 KiB LDS) and 3 MFMA products run off
// the same staged data (hh+hl+lh) -> 1.5x FLOP per staged byte vs R5 and no
// double-fetch of Xhi. n-major XCD swizzle: each XCD keeps one 4 MB A-panel
// L2-resident across 16 n-blocks; W planes (64 MB) stay L3-resident.
// Counted vmcnt (never 0 in main loop), 2-way-max LDS chunk swizzle,
// setprio around MFMA clusters. Top-k stays f64-exact (R2 proven).
// ---------------------------------------------------------------------------

typedef __bf16  bf16x8 __attribute__((ext_vector_type(8)));
typedef float   f32x4  __attribute__((ext_vector_type(4)));

__device__ __forceinline__ unsigned short f2bf(float f) {
    __hip_bfloat16 h = __float2bfloat16(f);
    return __builtin_bit_cast(unsigned short, h);
}
__device__ __forceinline__ float bf2f(unsigned short u) {
    __hip_bfloat16 h = __builtin_bit_cast(__hip_bfloat16, u);
    return __bfloat162float(h);
}

#define GLL16(g, l)                                                          \
    __builtin_amdgcn_global_load_lds(                                        \
        (const __attribute__((address_space(1))) unsigned int*)(g),          \
        (__attribute__((address_space(3))) unsigned int*)(l), 16, 0, 0)

// ---------------------------------------------------------------------------
// x [m][k] fp32 -> Xhi/Xlo [m][k] bf16 (pb folded in). Memory-bound.
// ---------------------------------------------------------------------------
__global__ __launch_bounds__(256)
void presplit_x(const float* __restrict__ x, const float* __restrict__ pb,
                unsigned short* __restrict__ Xhi, unsigned short* __restrict__ Xlo,
                int Kdim, size_t total) {
    size_t base = ((size_t)blockIdx.x * 256 + threadIdx.x) * 8;
    if (base >= total) return;
    int kcol = (int)(base % Kdim);
    __align__(16) unsigned short hi[8], lo[8];
    #pragma unroll
    for (int q = 0; q < 2; ++q) {
        float4 xv = *(const float4*)&x[base + q * 4];
        float4 pv = *(const float4*)&pb[kcol + q * 4];
        float v[4] = {xv.x - pv.x, xv.y - pv.y, xv.z - pv.z, xv.w - pv.w};
        #pragma unroll
        for (int r = 0; r < 4; ++r) {
            hi[q*4+r] = f2bf(v[r]);
            lo[q*4+r] = f2bf(v[r] - bf2f(hi[q*4+r]));
        }
    }
    *(uint4*)&Xhi[base] = *(uint4*)&hi[0];
    *(uint4*)&Xlo[base] = *(uint4*)&lo[0];
}

// ---------------------------------------------------------------------------
// W [k][n] fp32 -> Wt_hi/Wt_lo [n][k] bf16 (transpose + split).
// ---------------------------------------------------------------------------
__global__ __launch_bounds__(256)
void split_transpose_W(const float* __restrict__ W,
                       unsigned short* __restrict__ Wt_hi,
                       unsigned short* __restrict__ Wt_lo,
                       int N, int Kdim) {
    __shared__ float tile[64][65];
    const int tx = threadIdx.x;
    const int nB = blockIdx.x * 64;
    const int kB = blockIdx.y * 64;

    #pragma unroll
    for (int p = 0; p < 4; ++p) {
        int e  = tx + 256 * p;
        int kl = e >> 4;
        int n4 = (e & 15) << 2;
        float4 v = *(const float4*)&W[(size_t)(kB + kl) * N + nB + n4];
        tile[kl][n4 + 0] = v.x; tile[kl][n4 + 1] = v.y;
        tile[kl][n4 + 2] = v.z; tile[kl][n4 + 3] = v.w;
    }
    __syncthreads();

    #pragma unroll
    for (int p = 0; p < 4; ++p) {
        int e  = tx + 256 * p;
        int nl = e >> 4;
        int k4 = (e & 15) << 2;
        unsigned short hi[4], lo[4];
        #pragma unroll
        for (int r = 0; r < 4; ++r) {
            float f = tile[k4 + r][nl];
            hi[r] = f2bf(f);
            lo[r] = f2bf(f - bf2f(hi[r]));
        }
        size_t off = (size_t)(nB + nl) * Kdim + kB + k4;
        *(ushort4*)&Wt_hi[off] = *(ushort4*)&hi[0];
        *(ushort4*)&Wt_lo[off] = *(ushort4*)&lo[0];
    }
}

// ---------------------------------------------------------------------------
// 256x256 tile, BK=32, 8 waves (2Mx4N), 4 planes staged per K-tile (64 KB),
// double-buffered (128 KiB). 4 phases/K-tile, 24 MFMA/phase (3 products x
// 2m x 4n), 2 GLL16/thread/phase, counted vmcnt {-,4,-,2}.
// LDS chunk swizzle: phys = logical ^ (row&3) ^ ((row>>2)&3) -> <=2-way.
// Staging dest stays linear (global_load_lds); SOURCE chunk pre-swizzled.
// ---------------------------------------------------------------------------
__global__ __launch_bounds__(512, 2)
void gemm_presplit4p(const unsigned short* __restrict__ Xhi,
                     const unsigned short* __restrict__ Xlo,
                     const unsigned short* __restrict__ Wt_hi,
                     const unsigned short* __restrict__ Wt_lo,
                     const float* __restrict__ be,
                     float* __restrict__ out, int M, int N, int Kdim) {
    __shared__ unsigned short sAhi[2][256 * 32];
    __shared__ unsigned short sAlo[2][256 * 32];
    __shared__ unsigned short sBhi[2][256 * 32];
    __shared__ unsigned short sBlo[2][256 * 32];

    const int tx   = threadIdx.x;
    const int lane = tx & 63;
    const int wv   = tx >> 6;          // 0..7
    const int ln   = lane & 15;
    const int quad = lane >> 4;
    const int wm   = wv >> 2;          // 0..1 (M half)
    const int wn   = wv & 3;           // 0..3 (N quarter)

    // n-major bijective XCD swizzle: each XCD chunk walks n fastest ->
    // one 4 MB A-panel stays L2-resident per XCD; W re-reads hit L3.
    const int mT = M >> 8, nT = N >> 8, total = mT * nT;
    int wgid = blockIdx.y * gridDim.x + blockIdx.x;
    int xcd = wgid & 7, idx = wgid >> 3;
    int qq = total >> 3, rr = total & 7;
    int swz = (xcd < rr ? xcd * (qq + 1) : rr * (qq + 1) + (xcd - rr) * qq) + idx;
    const int mBase = (swz / nT) << 8;
    const int nBase = (swz % nT) << 8;

    // staging: 512 thr x 16B = one 8KB round = 128 rows x 64B
    const int srow = tx >> 2;          // 0..127 row-within-round
    const int lc   = tx & 3;           // dest 16B chunk (identity for GLL)
    const int ssw  = (srow & 3) ^ ((srow >> 2) & 3);
    const int slc  = (lc ^ ssw) << 3;  // pre-swizzled SOURCE chunk (elems)

    // fragment read: logical chunk = quad; physical = quad ^ swz(row),
    // swz(row) reduces to a pure function of ln for 16-aligned frag rows.
    const int swzl    = (ln & 3) ^ ((ln >> 2) & 3);
    const int fragoff = (quad ^ swzl) << 3;

    // B rounds r=0,1: rows [128r,128r+128)
#define STAGE_B(dst, r, src, kcol) do {                                       \
        int row_ = ((r) << 7) + srow;                                         \
        GLL16((src) + (size_t)(nBase + row_) * Kdim + (kcol) + slc,           \
              &(dst)[(row_ << 5) + (lc << 3)]);                               \
    } while (0)
    // A rounds r=0,1: rows [64r,64r+64) u [128+64r,128+64r+64)
    //   (phases 2r,2r+1 for BOTH wm halves)
#define STAGE_A(dst, r, src, kcol) do {                                       \
        int row_ = ((r) << 6) + srow + (srow & 64);                           \
        GLL16((src) + (size_t)(mBase + row_) * Kdim + (kcol) + slc,           \
              &(dst)[(row_ << 5) + (lc << 3)]);                               \
    } while (0)

    f32x4 acc[8][4] = {};

    const int NT = Kdim >> 5;          // K-tiles (BK=32); all 3 products per tile

    // prologue: stage tile 0 fully into buf 0
    STAGE_B(sBhi[0], 0, Wt_hi, 0); STAGE_B(sBhi[0], 1, Wt_hi, 0);
    STAGE_B(sBlo[0], 0, Wt_lo, 0); STAGE_B(sBlo[0], 1, Wt_lo, 0);
    STAGE_A(sAhi[0], 0, Xhi, 0);   STAGE_A(sAlo[0], 0, Xlo, 0);
    STAGE_A(sAhi[0], 1, Xhi, 0);   STAGE_A(sAlo[0], 1, Xlo, 0);
    asm volatile("s_waitcnt vmcnt(0)" ::: "memory");
    __builtin_amdgcn_s_barrier();
    __builtin_amdgcn_sched_barrier(0);

    for (int t = 0; t < NT; ++t) {
        const int cur = t & 1, nxt = cur ^ 1;
        const bool more = (t + 1 < NT);
        const int k1 = (t + 1) << 5;

        bf16x8 bhi[4], blo[4];         // read once at phase 0, held all tile
        #pragma unroll
        for (int q = 0; q < 4; ++q) {
            if (q == 0) {
                #pragma unroll
                for (int j = 0; j < 4; ++j) {
                    int rb = wn * 64 + j * 16 + ln;
                    bhi[j] = *(const bf16x8*)&sBhi[cur][(rb << 5) + fragoff];
                    blo[j] = *(const bf16x8*)&sBlo[cur][(rb << 5) + fragoff];
                }
            }
            bf16x8 ahi[2], alo[2];
            #pragma unroll
            for (int ii = 0; ii < 2; ++ii) {
                int ra = wm * 128 + (2 * q + ii) * 16 + ln;
                ahi[ii] = *(const bf16x8*)&sAhi[cur][(ra << 5) + fragoff];
                alo[ii] = *(const bf16x8*)&sAlo[cur][(ra << 5) + fragoff];
            }

            if (more) {                  // 2 staging rounds for tile t+1
                if (q == 0)      { STAGE_B(sBhi[nxt], 0, Wt_hi, k1); STAGE_B(sBhi[nxt], 1, Wt_hi, k1); }
                else if (q == 1) { STAGE_B(sBlo[nxt], 0, Wt_lo, k1); STAGE_B(sBlo[nxt], 1, Wt_lo, k1); }
                else if (q == 2) { STAGE_A(sAhi[nxt], 0, Xhi, k1);   STAGE_A(sAlo[nxt], 0, Xlo, k1); }
                else             { STAGE_A(sAhi[nxt], 1, Xhi, k1);   STAGE_A(sAlo[nxt], 1, Xlo, k1); }
            }

            __builtin_amdgcn_s_barrier();
            __builtin_amdgcn_s_setprio(1);
            // 24 MFMA: product-outer (8 independent chains between dependents)
            #pragma unroll
            for (int ii = 0; ii < 2; ++ii)
                #pragma unroll
                for (int j = 0; j < 4; ++j)
                    acc[2 * q + ii][j] = __builtin_amdgcn_mfma_f32_16x16x32_bf16(
                        ahi[ii], bhi[j], acc[2 * q + ii][j], 0, 0, 0);
            #pragma unroll
            for (int ii = 0; ii < 2; ++ii)
                #pragma unroll
                for (int j = 0; j < 4; ++j)
                    acc[2 * q + ii][j] = __builtin_amdgcn_mfma_f32_16x16x32_bf16(
                        ahi[ii], blo[j], acc[2 * q + ii][j], 0, 0, 0);
            #pragma unroll
            for (int ii = 0; ii < 2; ++ii)
                #pragma unroll
                for (int j = 0; j < 4; ++j)
                    acc[2 * q + ii][j] = __builtin_amdgcn_mfma_f32_16x16x32_bf16(
                        alo[ii], bhi[j], acc[2 * q + ii][j], 0, 0, 0);
            __builtin_amdgcn_s_setprio(0);

            // counted waits: loads 1-6 of tile t+1 must land before its ph0,
            // loads 7,8 before its ph2. Never drain to 0 while staging.
            if (more) {
                if (q == 1)      asm volatile("s_waitcnt vmcnt(4)" ::: "memory");
                else if (q == 3) asm volatile("s_waitcnt vmcnt(2)" ::: "memory");
            } else if (q == 1) {
                asm volatile("s_waitcnt vmcnt(0)" ::: "memory");
            }
            __builtin_amdgcn_s_barrier();
            __builtin_amdgcn_sched_barrier(0);
        }
    }

    // epilogue: + b_enc, relu, store (C/D: col=lane&15, row=quad*4+reg)
    #pragma unroll
    for (int j = 0; j < 4; ++j) {
        int n = nBase + wn * 64 + j * 16 + ln;
        float bev = be[n];
        #pragma unroll
        for (int i = 0; i < 8; ++i) {
            #pragma unroll
            for (int r = 0; r < 4; ++r) {
                int m = mBase + wm * 128 + i * 16 + quad * 4 + r;
                out[(size_t)m * N + n] = fmaxf(acc[i][j][r] + bev, 0.f);
            }
        }
    }
#undef STAGE_B
#undef STAGE_A
}

// ---------------------------------------------------------------------------
// R3 fallback GEMM (on-the-fly A split) — used only if ws can't hold X planes
// or the shape isn't 256/32-divisible.
// ---------------------------------------------------------------------------
__global__ __launch_bounds__(256)
void gemm_split_bf16(const float* __restrict__ x, const float* __restrict__ pb,
                     const unsigned short* __restrict__ Wt_hi,
                     const unsigned short* __restrict__ Wt_lo,
                     const float* __restrict__ be,
                     float* __restrict__ out, int M, int N, int Kdim) {
    __shared__ unsigned short sAhi[128][32];
    __shared__ unsigned short sAlo[128][32];
    __shared__ unsigned short sBhi[128][32];
    __shared__ unsigned short sBlo[128][32];

    const int tx    = threadIdx.x;
    const int nBase = blockIdx.x * 128;
    const int mBase = blockIdx.y * 128;
    const int wv    = tx >> 6;
    const int lane  = tx & 63;
    const int ln    = lane & 15;
    const int quad  = lane >> 4;
    const int wm    = wv >> 1;
    const int wn    = wv & 1;
    const int am = tx >> 1;
    const int ak = (tx & 1) * 16;
    const int bn  = wv * 16 + (lane >> 2);
    const int bk8 = (lane & 3) * 8;

    f32x4 acc[4][4] = {};

    for (int k0 = 0; k0 < Kdim; k0 += 32) {
        __syncthreads();
        #pragma unroll
        for (int r = 0; r < 2; ++r) {
            int nrow = r * 64 + bn;
            size_t goff = (size_t)(nBase + nrow) * Kdim + k0 + bk8;
            GLL16(&Wt_hi[goff], &sBhi[nrow][bk8]);
            GLL16(&Wt_lo[goff], &sBlo[nrow][bk8]);
        }
        {
            const float* xrow = x  + (size_t)(mBase + am) * Kdim + k0 + ak;
            const float* pbp  = pb + k0 + ak;
            float v[16];
            #pragma unroll
            for (int q = 0; q < 4; ++q) {
                float4 xv = *(const float4*)(xrow + q * 4);
                float4 pv = *(const float4*)(pbp + q * 4);
                v[q*4+0] = xv.x - pv.x; v[q*4+1] = xv.y - pv.y;
                v[q*4+2] = xv.z - pv.z; v[q*4+3] = xv.w - pv.w;
            }
            __align__(16) unsigned short hi[16], lo[16];
            #pragma unroll
            for (int q = 0; q < 16; ++q) {
                hi[q] = f2bf(v[q]);
                lo[q] = f2bf(v[q] - bf2f(hi[q]));
            }
            *(uint4*)&sAhi[am][ak]     = *(uint4*)&hi[0];
            *(uint4*)&sAhi[am][ak + 8] = *(uint4*)&hi[8];
            *(uint4*)&sAlo[am][ak]     = *(uint4*)&lo[0];
            *(uint4*)&sAlo[am][ak + 8] = *(uint4*)&lo[8];
        }
        __syncthreads();

        bf16x8 ahi[4], alo[4], bhi[4], blo[4];
        #pragma unroll
        for (int i = 0; i < 4; ++i) {
            int m = wm * 64 + i * 16 + ln;
            ahi[i] = *(const bf16x8*)&sAhi[m][quad * 8];
            alo[i] = *(const bf16x8*)&sAlo[m][quad * 8];
        }
        #pragma unroll
        for (int j = 0; j < 4; ++j) {
            int n = wn * 64 + j * 16 + ln;
            bhi[j] = *(const bf16x8*)&sBhi[n][quad * 8];
            blo[j] = *(const bf16x8*)&sBlo[n][quad * 8];
        }
        #pragma unroll
        for (int i = 0; i < 4; ++i)
            #pragma unroll
            for (int j = 0; j < 4; ++j) {
                acc[i][j] = __builtin_amdgcn_mfma_f32_16x16x32_bf16(ahi[i], bhi[j], acc[i][j], 0, 0, 0);
                acc[i][j] = __builtin_amdgcn_mfma_f32_16x16x32_bf16(ahi[i], blo[j], acc[i][j], 0, 0, 0);
                acc[i][j] = __builtin_amdgcn_mfma_f32_16x16x32_bf16(alo[i], bhi[j], acc[i][j], 0, 0, 0);
            }
    }

    #pragma unroll
    for (int j = 0; j < 4; ++j) {
        int n = nBase + wn * 64 + j * 16 + ln;
        float bev = be[n];
        #pragma unroll
        for (int i = 0; i < 4; ++i)
            #pragma unroll
            for (int r = 0; r < 4; ++r) {
                int m = mBase + wm * 64 + i * 16 + quad * 4 + r;
                out[(size_t)m * N + n] = fmaxf(acc[i][j][r] + bev, 0.f);
            }
    }
}

// ---------------------------------------------------------------------------
// Top-k mask with f64-exact boundary decisions (R2, proven).
// ---------------------------------------------------------------------------
#define BAND    2e-4f
#define AMB_CAP 64

__global__ __launch_bounds__(256)
void topk_mask_exact(const float* __restrict__ x, const float* __restrict__ pb,
                     const float* __restrict__ W, const float* __restrict__ be,
                     float* __restrict__ out, int N, int Kdim, int Ksel) {
    __shared__ float    vals[4096];
    __shared__ unsigned hist[256];
    __shared__ unsigned s_prefix;
    __shared__ int      s_k, s_done;
    __shared__ int      s_nhi, s_namb;
    __shared__ int      amb_idx[AMB_CAP];
    __shared__ double   amb_d[AMB_CAP];
    __shared__ int      amb_keep[AMB_CAP];
    __shared__ double   red[4];

    const int tx  = threadIdx.x;
    const int row = blockIdx.x;
    float* rowp = out + (size_t)row * N;

    #pragma unroll
    for (int p = 0; p < 4; ++p) {
        int i = (tx + 256 * p) << 2;
        *(float4*)&vals[i] = *(const float4*)&rowp[i];
    }
    if (tx == 0) { s_done = 0; s_nhi = 0; s_namb = 0; }
    __syncthreads();

    unsigned prefix = 0, prefix_mask = 0;
    int kneed_r = Ksel;
    for (int shift = 24; shift >= 0; shift -= 8) {
        hist[tx] = 0;
        __syncthreads();
        #pragma unroll
        for (int p = 0; p < 16; ++p) {
            unsigned u = __float_as_uint(vals[tx + 256 * p]);
            if (u != 0u && (u & prefix_mask) == prefix)
                atomicAdd(&hist[(u >> shift) & 255u], 1u);
        }
        __syncthreads();
        if (tx == 0) {
            int cum = 0, b;
            for (b = 255; b >= 0; --b) { cum += (int)hist[b]; if (cum >= kneed_r) break; }
            if (b < 0) s_done = 1;
            else { s_prefix = prefix | ((unsigned)b << shift); s_k = kneed_r - (cum - (int)hist[b]); }
        }
        __syncthreads();
        if (s_done) { prefix = 0; break; }
        prefix = s_prefix;
        kneed_r = s_k;
        prefix_mask |= (0xFFu << shift);
        __syncthreads();
    }
    const float thr = __uint_as_float(prefix);

    if (thr < 0.01f) {
        #pragma unroll
        for (int p = 0; p < 4; ++p) {
            int i = (tx + 256 * p) << 2;
            float4 v = *(float4*)&vals[i];
            v.x = (v.x >= thr) ? v.x : 0.f;
            v.y = (v.y >= thr) ? v.y : 0.f;
            v.z = (v.z >= thr) ? v.z : 0.f;
            v.w = (v.w >= thr) ? v.w : 0.f;
            *(float4*)&rowp[i] = v;
        }
        return;
    }

    int my_hi = 0;
    #pragma unroll
    for (int p = 0; p < 16; ++p) {
        float v = vals[tx + 256 * p];
        if (v > thr + BAND) my_hi++;
        else if (v >= thr - BAND) {
            int slot = atomicAdd(&s_namb, 1);
            if (slot < AMB_CAP) amb_idx[slot] = tx + 256 * p;
        }
    }
    atomicAdd(&s_nhi, my_hi);
    __syncthreads();

    const int nhi   = s_nhi;
    const int namb  = (s_namb < AMB_CAP) ? s_namb : AMB_CAP;
    const int kneed = Ksel - nhi;
    const bool fallback = (s_namb > AMB_CAP) || (kneed < 0) || (kneed > s_namb);

    if (fallback) {
        #pragma unroll
        for (int p = 0; p < 16; ++p) {
            int i = tx + 256 * p;
            float v = vals[i];
            rowp[i] = (v >= thr) ? v : 0.f;
        }
        return;
    }

    if (namb > kneed) {
        for (int j = 0; j < namb; ++j) {
            const int n = amb_idx[j];
            double partial = 0.0;
            for (int p = 0; p < Kdim / 256; ++p) {
                int k = tx + 256 * p;
                partial += ((double)x[(size_t)row * Kdim + k] - (double)pb[k]) *
                           (double)W[(size_t)k * N + n];
            }
            #pragma unroll
            for (int off = 32; off > 0; off >>= 1) partial += __shfl_down(partial, off);
            if ((tx & 63) == 0) red[tx >> 6] = partial;
            __syncthreads();
            if (tx == 0) amb_d[j] = red[0] + red[1] + red[2] + red[3] + (double)be[n];
            __syncthreads();
        }
        if (tx == 0) {
            for (int j = 0; j < namb; ++j) {
                int greater = 0;
                for (int l = 0; l < namb; ++l)
                    if (amb_d[l] > amb_d[j]) greater++;
                amb_keep[j] = (greater < kneed) ? 1 : 0;
            }
        }
        __syncthreads();
    } else {
        for (int j = tx; j < namb; j += 256) amb_keep[j] = 1;
        __syncthreads();
    }

    #pragma unroll
    for (int p = 0; p < 16; ++p) {
        int i = tx + 256 * p;
        float v = vals[i];
        float o;
        if (v > thr + BAND) o = v;
        else if (v < thr - BAND) o = 0.f;
        else {
            int keep = 0;
            for (int j = 0; j < namb; ++j)
                if (amb_idx[j] == i) { keep = amb_keep[j]; break; }
            o = keep ? v : 0.f;
        }
        rowp[i] = o;
    }
}

extern "C" void kernel_launch(void* const* d_in, const int* in_sizes, int n_in,
                              void* d_out, int out_size, void* d_ws, size_t ws_size,
                              hipStream_t stream) {
    const float* x  = (const float*)d_in[0];
    const float* pb = (const float*)d_in[1];
    const float* W  = (const float*)d_in[2];
    const float* be = (const float*)d_in[3];
    float* out = (float*)d_out;

    const int D = in_sizes[1];          // 4096
    const int N = in_sizes[3];          // 4096
    const int M = in_sizes[0] / D;      // 16384

    const size_t szW = (size_t)N * D;   // elements per W plane
    const size_t szX = (size_t)M * D;   // elements per X plane
    const size_t needW    = 2ull * szW * sizeof(unsigned short);            // 64 MB
    const size_t needFull = needW + 2ull * szX * sizeof(unsigned short);    // 332 MB

    const bool div256 = (M % 256 == 0) && (N % 256 == 0) && (D % 32 == 0);

    if (ws_size >= needFull && div256) {
        unsigned short* Wt_hi = (unsigned short*)d_ws;
        unsigned short* Wt_lo = Wt_hi + szW;
        unsigned short* Xhi   = Wt_lo + szW;
        unsigned short* Xlo   = Xhi + szX;
        split_transpose_W<<<dim3(N / 64, D / 64), 256, 0, stream>>>(W, Wt_hi, Wt_lo, N, D);
        {
            size_t total = szX;
            int blocks = (int)((total / 8 + 255) / 256);
            presplit_x<<<blocks, 256, 0, stream>>>(x, pb, Xhi, Xlo, D, total);
        }
        gemm_presplit4p<<<dim3(N / 256, M / 256), 512, 0, stream>>>(
            Xhi, Xlo, Wt_hi, Wt_lo, be, out, M, N, D);
    } else {
        unsigned short* Wt_hi = (unsigned short*)d_ws;
        unsigned short* Wt_lo = Wt_hi + szW;
        split_transpose_W<<<dim3(N / 64, D / 64), 256, 0, stream>>>(W, Wt_hi, Wt_lo, N, D);
        gemm_split_bf16<<<dim3(N / 128, M / 128), 256, 0, stream>>>(
            x, pb, Wt_hi, Wt_lo, be, out, M, N, D);
    }
    topk_mask_exact<<<M, 256, 0, stream>>>(x, pb, W, be, out, N, D, 128);
}

// Round 3
// 2058.830 us; speedup vs baseline: 1.2992x; 1.1072x over previous
//
#include <hip/hip_runtime.h>
#include <hip/hip_bf16.h>

// ---------------------------------------------------------------------------
// y = relu((x - pb) @ W + be); thr = 128th largest per row; out = y*(y>=thr).
// M=16384, K=4096, N=4096, fp32 in/out.
//
// R7: (a) GEMM keeps R6's 4-plane/3-product staging economy but stores the
// hi|lo planes INTERLEAVED in 128-byte LDS rows ([hi c0..3 | lo c0..3]) with
// the R5-proven 3-bit XOR chunk swizzle (row&7) -> conflict-free ds_read_b128
// (R5 measured 0; R6's 64B rows measured 1e8). Staging dest stays linear for
// global_load_lds; the per-lane GLOBAL source picks plane+chunk via the
// inverse XOR. Counted vmcnt {4,5,6,3}, setprio, n-major XCD swizzle kept.
// (b) top-k threshold now via register-resident bit-bisection (31 iters of
// block-count) instead of LDS-atomic radix histogram (hot-bin serialization);
// bit-identical threshold, proven f64 band machinery unchanged.
// ---------------------------------------------------------------------------

typedef __bf16  bf16x8 __attribute__((ext_vector_type(8)));
typedef float   f32x4  __attribute__((ext_vector_type(4)));

__device__ __forceinline__ unsigned short f2bf(float f) {
    __hip_bfloat16 h = __float2bfloat16(f);
    return __builtin_bit_cast(unsigned short, h);
}
__device__ __forceinline__ float bf2f(unsigned short u) {
    __hip_bfloat16 h = __builtin_bit_cast(__hip_bfloat16, u);
    return __bfloat162float(h);
}

#define GLL16(g, l)                                                          \
    __builtin_amdgcn_global_load_lds(                                        \
        (const __attribute__((address_space(1))) unsigned int*)(g),          \
        (__attribute__((address_space(3))) unsigned int*)(l), 16, 0, 0)

// ---------------------------------------------------------------------------
// x [m][k] fp32 -> Xhi/Xlo [m][k] bf16 (pb folded in). Memory-bound.
// ---------------------------------------------------------------------------
__global__ __launch_bounds__(256)
void presplit_x(const float* __restrict__ x, const float* __restrict__ pb,
                unsigned short* __restrict__ Xhi, unsigned short* __restrict__ Xlo,
                int Kdim, size_t total) {
    size_t base = ((size_t)blockIdx.x * 256 + threadIdx.x) * 8;
    if (base >= total) return;
    int kcol = (int)(base % Kdim);
    __align__(16) unsigned short hi[8], lo[8];
    #pragma unroll
    for (int q = 0; q < 2; ++q) {
        float4 xv = *(const float4*)&x[base + q * 4];
        float4 pv = *(const float4*)&pb[kcol + q * 4];
        float v[4] = {xv.x - pv.x, xv.y - pv.y, xv.z - pv.z, xv.w - pv.w};
        #pragma unroll
        for (int r = 0; r < 4; ++r) {
            hi[q*4+r] = f2bf(v[r]);
            lo[q*4+r] = f2bf(v[r] - bf2f(hi[q*4+r]));
        }
    }
    *(uint4*)&Xhi[base] = *(uint4*)&hi[0];
    *(uint4*)&Xlo[base] = *(uint4*)&lo[0];
}

// ---------------------------------------------------------------------------
// W [k][n] fp32 -> Wt_hi/Wt_lo [n][k] bf16 (transpose + split).
// ---------------------------------------------------------------------------
__global__ __launch_bounds__(256)
void split_transpose_W(const float* __restrict__ W,
                       unsigned short* __restrict__ Wt_hi,
                       unsigned short* __restrict__ Wt_lo,
                       int N, int Kdim) {
    __shared__ float tile[64][65];
    const int tx = threadIdx.x;
    const int nB = blockIdx.x * 64;
    const int kB = blockIdx.y * 64;

    #pragma unroll
    for (int p = 0; p < 4; ++p) {
        int e  = tx + 256 * p;
        int kl = e >> 4;
        int n4 = (e & 15) << 2;
        float4 v = *(const float4*)&W[(size_t)(kB + kl) * N + nB + n4];
        tile[kl][n4 + 0] = v.x; tile[kl][n4 + 1] = v.y;
        tile[kl][n4 + 2] = v.z; tile[kl][n4 + 3] = v.w;
    }
    __syncthreads();

    #pragma unroll
    for (int p = 0; p < 4; ++p) {
        int e  = tx + 256 * p;
        int nl = e >> 4;
        int k4 = (e & 15) << 2;
        unsigned short hi[4], lo[4];
        #pragma unroll
        for (int r = 0; r < 4; ++r) {
            float f = tile[k4 + r][nl];
            hi[r] = f2bf(f);
            lo[r] = f2bf(f - bf2f(hi[r]));
        }
        size_t off = (size_t)(nB + nl) * Kdim + kB + k4;
        *(ushort4*)&Wt_hi[off] = *(ushort4*)&hi[0];
        *(ushort4*)&Wt_lo[off] = *(ushort4*)&lo[0];
    }
}

// ---------------------------------------------------------------------------
// 256x256 tile, BK=32, 8 waves (2Mx4N). LDS rows are 128B = [hi c0..3|lo c0..3]
// with phys_chunk = logical ^ (row&7)  (R5-proven conflict-free pattern).
// 4 phases/K-tile, 24 MFMA/phase, 2 GLL16/thread/phase, counted vmcnt
// {4,5,6,3} (issue order per tile: B0 B1 | B2 B3 | A0 A1 | A2 A3; A round r
// is consumed at phase r of the next tile).
// ---------------------------------------------------------------------------
__global__ __launch_bounds__(512, 2)
void gemm_presplit_i(const unsigned short* __restrict__ Xhi,
                     const unsigned short* __restrict__ Xlo,
                     const unsigned short* __restrict__ Wt_hi,
                     const unsigned short* __restrict__ Wt_lo,
                     const float* __restrict__ be,
                     float* __restrict__ out, int M, int N, int Kdim) {
    __shared__ unsigned short sA[2][256 * 64];   // 256 rows x 128B
    __shared__ unsigned short sB[2][256 * 64];

    const int tx   = threadIdx.x;
    const int lane = tx & 63;
    const int wv   = tx >> 6;          // 0..7
    const int ln   = lane & 15;
    const int quad = lane >> 4;
    const int wm   = wv >> 2;          // 0..1 (M half)
    const int wn   = wv & 3;           // 0..3 (N quarter)

    // n-major bijective XCD swizzle: one A-panel per XCD stays L2-resident.
    const int mT = M >> 8, nT = N >> 8, total = mT * nT;
    int wgid = blockIdx.y * gridDim.x + blockIdx.x;
    int xcd = wgid & 7, idx = wgid >> 3;
    int qq = total >> 3, rr_ = total & 7;
    int swz = (xcd < rr_ ? xcd * (qq + 1) : rr_ * (qq + 1) + (xcd - rr_) * qq) + idx;
    const int mBase = (swz / nT) << 8;
    const int nBase = (swz % nT) << 8;

    // staging: 512 thr x 16B = 8KB round = 64 rows x 128B
    const int rr  = tx >> 3;           // 0..63 row-within-round
    const int lc8 = tx & 7;            // dest (physical) 16B chunk, linear
    const int lgc = lc8 ^ (rr & 7);    // logical chunk held at this dest slot
    const unsigned short* aSrc = (lgc & 4) ? Xlo : Xhi;
    const unsigned short* bSrc = (lgc & 4) ? Wt_lo : Wt_hi;
    const int srcoff = (lgc & 3) << 3;            // element offset within k-tile
    const int arow_b = (rr & 31) + ((rr & 32) << 2);  // + (r<<5): covers both wm halves

    // fragment read: logical chunk = quad (hi) / 4+quad (lo); phys = ^ (row&7);
    // frag rows are 16-aligned + ln, so row&7 == ln&7.
    const int pA = (quad ^ (ln & 7)) << 3;        // hi-plane phys offset (shorts)
    // lo-plane offset = pA ^ 32  (4<<3)

#define STAGE_B(bufp, r, k0_) do {                                            \
        int row_ = ((r) << 6) + rr;                                           \
        GLL16(bSrc + (size_t)(nBase + row_) * Kdim + (k0_) + srcoff,          \
              &sB[bufp][(row_ << 6) + (lc8 << 3)]);                           \
    } while (0)
#define STAGE_A(bufp, r, k0_) do {                                            \
        int row_ = ((r) << 5) + arow_b;                                       \
        GLL16(aSrc + (size_t)(mBase + row_) * Kdim + (k0_) + srcoff,          \
              &sA[bufp][(row_ << 6) + (lc8 << 3)]);                           \
    } while (0)

    f32x4 acc[8][4] = {};

    const int NT = Kdim >> 5;          // K-tiles (BK=32)

    // prologue: stage tile 0 fully into buf 0 (order B0..B3, A0..A3)
    STAGE_B(0, 0, 0); STAGE_B(0, 1, 0); STAGE_B(0, 2, 0); STAGE_B(0, 3, 0);
    STAGE_A(0, 0, 0); STAGE_A(0, 1, 0); STAGE_A(0, 2, 0); STAGE_A(0, 3, 0);
    asm volatile("s_waitcnt vmcnt(0)" ::: "memory");
    __builtin_amdgcn_s_barrier();
    __builtin_amdgcn_sched_barrier(0);

    for (int t = 0; t < NT; ++t) {
        const int cur = t & 1, nxt = cur ^ 1;
        const bool more = (t + 1 < NT);
        const int k1 = (t + 1) << 5;

        bf16x8 bhi[4], blo[4];         // read once at phase 0, held all tile
        #pragma unroll
        for (int q = 0; q < 4; ++q) {
            if (q == 0) {
                #pragma unroll
                for (int j = 0; j < 4; ++j) {
                    int rb = wn * 64 + j * 16 + ln;
                    bhi[j] = *(const bf16x8*)&sB[cur][(rb << 6) + pA];
                    blo[j] = *(const bf16x8*)&sB[cur][(rb << 6) + (pA ^ 32)];
                }
            }
            bf16x8 ahi[2], alo[2];
            #pragma unroll
            for (int ii = 0; ii < 2; ++ii) {
                int ra = wm * 128 + (2 * q + ii) * 16 + ln;
                ahi[ii] = *(const bf16x8*)&sA[cur][(ra << 6) + pA];
                alo[ii] = *(const bf16x8*)&sA[cur][(ra << 6) + (pA ^ 32)];
            }

            if (more) {                  // 2 staging rounds for tile t+1
                if (q == 0)      { STAGE_B(nxt, 0, k1); STAGE_B(nxt, 1, k1); }
                else if (q == 1) { STAGE_B(nxt, 2, k1); STAGE_B(nxt, 3, k1); }
                else if (q == 2) { STAGE_A(nxt, 0, k1); STAGE_A(nxt, 1, k1); }
                else             { STAGE_A(nxt, 2, k1); STAGE_A(nxt, 3, k1); }
            }

            __builtin_amdgcn_s_barrier();
            __builtin_amdgcn_s_setprio(1);
            #pragma unroll
            for (int ii = 0; ii < 2; ++ii)
                #pragma unroll
                for (int j = 0; j < 4; ++j)
                    acc[2 * q + ii][j] = __builtin_amdgcn_mfma_f32_16x16x32_bf16(
                        ahi[ii], bhi[j], acc[2 * q + ii][j], 0, 0, 0);
            #pragma unroll
            for (int ii = 0; ii < 2; ++ii)
                #pragma unroll
                for (int j = 0; j < 4; ++j)
                    acc[2 * q + ii][j] = __builtin_amdgcn_mfma_f32_16x16x32_bf16(
                        ahi[ii], blo[j], acc[2 * q + ii][j], 0, 0, 0);
            #pragma unroll
            for (int ii = 0; ii < 2; ++ii)
                #pragma unroll
                for (int j = 0; j < 4; ++j)
                    acc[2 * q + ii][j] = __builtin_amdgcn_mfma_f32_16x16x32_bf16(
                        alo[ii], bhi[j], acc[2 * q + ii][j], 0, 0, 0);
            __builtin_amdgcn_s_setprio(0);

            // counted waits guarding the NEXT phase's ds_reads (per-thread
            // issue order per tile: B0 B1 B2 B3 A0 A1 A2 A3):
            if (more) {
                if (q == 0)      asm volatile("s_waitcnt vmcnt(4)" ::: "memory");
                else if (q == 1) asm volatile("s_waitcnt vmcnt(5)" ::: "memory");
                else if (q == 2) asm volatile("s_waitcnt vmcnt(6)" ::: "memory");
                else             asm volatile("s_waitcnt vmcnt(3)" ::: "memory");
            } else {
                if (q == 0)      asm volatile("s_waitcnt vmcnt(2)" ::: "memory");
                else if (q == 1) asm volatile("s_waitcnt vmcnt(1)" ::: "memory");
                else if (q == 2) asm volatile("s_waitcnt vmcnt(0)" ::: "memory");
            }
            __builtin_amdgcn_s_barrier();
            __builtin_amdgcn_sched_barrier(0);
        }
    }

    // epilogue: + b_enc, relu, store (C/D: col=lane&15, row=quad*4+reg)
    #pragma unroll
    for (int j = 0; j < 4; ++j) {
        int n = nBase + wn * 64 + j * 16 + ln;
        float bev = be[n];
        #pragma unroll
        for (int i = 0; i < 8; ++i) {
            #pragma unroll
            for (int r = 0; r < 4; ++r) {
                int m = mBase + wm * 128 + i * 16 + quad * 4 + r;
                out[(size_t)m * N + n] = fmaxf(acc[i][j][r] + bev, 0.f);
            }
        }
    }
#undef STAGE_B
#undef STAGE_A
}

// ---------------------------------------------------------------------------
// R3 fallback GEMM (on-the-fly A split) — used only if ws can't hold X planes
// or the shape isn't 256/32-divisible.
// ---------------------------------------------------------------------------
__global__ __launch_bounds__(256)
void gemm_split_bf16(const float* __restrict__ x, const float* __restrict__ pb,
                     const unsigned short* __restrict__ Wt_hi,
                     const unsigned short* __restrict__ Wt_lo,
                     const float* __restrict__ be,
                     float* __restrict__ out, int M, int N, int Kdim) {
    __shared__ unsigned short sAhi[128][32];
    __shared__ unsigned short sAlo[128][32];
    __shared__ unsigned short sBhi[128][32];
    __shared__ unsigned short sBlo[128][32];

    const int tx    = threadIdx.x;
    const int nBase = blockIdx.x * 128;
    const int mBase = blockIdx.y * 128;
    const int wv    = tx >> 6;
    const int lane  = tx & 63;
    const int ln    = lane & 15;
    const int quad  = lane >> 4;
    const int wm    = wv >> 1;
    const int wn    = wv & 1;
    const int am = tx >> 1;
    const int ak = (tx & 1) * 16;
    const int bn  = wv * 16 + (lane >> 2);
    const int bk8 = (lane & 3) * 8;

    f32x4 acc[4][4] = {};

    for (int k0 = 0; k0 < Kdim; k0 += 32) {
        __syncthreads();
        #pragma unroll
        for (int r = 0; r < 2; ++r) {
            int nrow = r * 64 + bn;
            size_t goff = (size_t)(nBase + nrow) * Kdim + k0 + bk8;
            GLL16(&Wt_hi[goff], &sBhi[nrow][bk8]);
            GLL16(&Wt_lo[goff], &sBlo[nrow][bk8]);
        }
        {
            const float* xrow = x  + (size_t)(mBase + am) * Kdim + k0 + ak;
            const float* pbp  = pb + k0 + ak;
            float v[16];
            #pragma unroll
            for (int q = 0; q < 4; ++q) {
                float4 xv = *(const float4*)(xrow + q * 4);
                float4 pv = *(const float4*)(pbp + q * 4);
                v[q*4+0] = xv.x - pv.x; v[q*4+1] = xv.y - pv.y;
                v[q*4+2] = xv.z - pv.z; v[q*4+3] = xv.w - pv.w;
            }
            __align__(16) unsigned short hi[16], lo[16];
            #pragma unroll
            for (int q = 0; q < 16; ++q) {
                hi[q] = f2bf(v[q]);
                lo[q] = f2bf(v[q] - bf2f(hi[q]));
            }
            *(uint4*)&sAhi[am][ak]     = *(uint4*)&hi[0];
            *(uint4*)&sAhi[am][ak + 8] = *(uint4*)&hi[8];
            *(uint4*)&sAlo[am][ak]     = *(uint4*)&lo[0];
            *(uint4*)&sAlo[am][ak + 8] = *(uint4*)&lo[8];
        }
        __syncthreads();

        bf16x8 ahi[4], alo[4], bhi[4], blo[4];
        #pragma unroll
        for (int i = 0; i < 4; ++i) {
            int m = wm * 64 + i * 16 + ln;
            ahi[i] = *(const bf16x8*)&sAhi[m][quad * 8];
            alo[i] = *(const bf16x8*)&sAlo[m][quad * 8];
        }
        #pragma unroll
        for (int j = 0; j < 4; ++j) {
            int n = wn * 64 + j * 16 + ln;
            bhi[j] = *(const bf16x8*)&sBhi[n][quad * 8];
            blo[j] = *(const bf16x8*)&sBlo[n][quad * 8];
        }
        #pragma unroll
        for (int i = 0; i < 4; ++i)
            #pragma unroll
            for (int j = 0; j < 4; ++j) {
                acc[i][j] = __builtin_amdgcn_mfma_f32_16x16x32_bf16(ahi[i], bhi[j], acc[i][j], 0, 0, 0);
                acc[i][j] = __builtin_amdgcn_mfma_f32_16x16x32_bf16(ahi[i], blo[j], acc[i][j], 0, 0, 0);
                acc[i][j] = __builtin_amdgcn_mfma_f32_16x16x32_bf16(alo[i], bhi[j], acc[i][j], 0, 0, 0);
            }
    }

    #pragma unroll
    for (int j = 0; j < 4; ++j) {
        int n = nBase + wn * 64 + j * 16 + ln;
        float bev = be[n];
        #pragma unroll
        for (int i = 0; i < 4; ++i)
            #pragma unroll
            for (int r = 0; r < 4; ++r) {
                int m = mBase + wm * 64 + i * 16 + quad * 4 + r;
                out[(size_t)m * N + n] = fmaxf(acc[i][j][r] + bev, 0.f);
            }
    }
}

// ---------------------------------------------------------------------------
// Top-k mask. Threshold by register-resident bit-bisection (exact: positive
// float order == uint order), then the proven R2 f64 band machinery.
// ---------------------------------------------------------------------------
#define BAND    2e-4f
#define AMB_CAP 64

__global__ __launch_bounds__(256)
void topk_mask_exact(const float* __restrict__ x, const float* __restrict__ pb,
                     const float* __restrict__ W, const float* __restrict__ be,
                     float* __restrict__ out, int N, int Kdim, int Ksel) {
    __shared__ int    s_red[4];
    __shared__ int    s_nhi, s_namb;
    __shared__ int    amb_idx[AMB_CAP];
    __shared__ double amb_d[AMB_CAP];
    __shared__ int    amb_keep[AMB_CAP];
    __shared__ double dred[4];

    const int tx  = threadIdx.x;
    const int row = blockIdx.x;
    float* rowp = out + (size_t)row * N;

    // 16 values per thread, in registers: global idx g = 4*(tx+256p)+r
    float v[16];
    #pragma unroll
    for (int p = 0; p < 4; ++p) {
        float4 f = *(const float4*)&rowp[(tx + 256 * p) << 2];
        v[p*4+0] = f.x; v[p*4+1] = f.y; v[p*4+2] = f.z; v[p*4+3] = f.w;
    }
    unsigned uv[16];
    #pragma unroll
    for (int i = 0; i < 16; ++i) uv[i] = __float_as_uint(v[i]);

    // nonzero count
    int c0 = 0;
    #pragma unroll
    for (int i = 0; i < 16; ++i) c0 += (uv[i] != 0u) ? 1 : 0;
    #pragma unroll
    for (int off = 32; off > 0; off >>= 1) c0 += __shfl_down(c0, off);
    if ((tx & 63) == 0) s_red[tx >> 6] = c0;
    __syncthreads();
    const int total_nz = s_red[0] + s_red[1] + s_red[2] + s_red[3];

    // bisection: largest u>0 with count(val_uint >= u) >= Ksel
    unsigned thr_u = 0;
    if (total_nz >= Ksel) {
        unsigned blo_ = 1u, bhi_ = 0x7f7fffffu;
        while (blo_ < bhi_) {
            unsigned mid = blo_ + ((bhi_ - blo_ + 1) >> 1);
            int cc = 0;
            #pragma unroll
            for (int i = 0; i < 16; ++i) cc += (uv[i] >= mid) ? 1 : 0;
            #pragma unroll
            for (int off = 32; off > 0; off >>= 1) cc += __shfl_down(cc, off);
            __syncthreads();              // previous s_red reads done
            if ((tx & 63) == 0) s_red[tx >> 6] = cc;
            __syncthreads();
            int cnt = s_red[0] + s_red[1] + s_red[2] + s_red[3];
            if (cnt >= Ksel) blo_ = mid; else bhi_ = mid - 1;
        }
        thr_u = blo_;
    }
    const float thr = __uint_as_float(thr_u);

    if (thr < 0.01f) {
        #pragma unroll
        for (int p = 0; p < 4; ++p) {
            float4 o;
            o.x = (v[p*4+0] >= thr) ? v[p*4+0] : 0.f;
            o.y = (v[p*4+1] >= thr) ? v[p*4+1] : 0.f;
            o.z = (v[p*4+2] >= thr) ? v[p*4+2] : 0.f;
            o.w = (v[p*4+3] >= thr) ? v[p*4+3] : 0.f;
            *(float4*)&rowp[(tx + 256 * p) << 2] = o;
        }
        return;
    }

    if (tx == 0) { s_nhi = 0; s_namb = 0; }
    __syncthreads();

    int my_hi = 0;
    #pragma unroll
    for (int i = 0; i < 16; ++i) {
        float val = v[i];
        if (val > thr + BAND) my_hi++;
        else if (val >= thr - BAND) {
            int slot = atomicAdd(&s_namb, 1);
            if (slot < AMB_CAP) amb_idx[slot] = ((tx + 256 * (i >> 2)) << 2) + (i & 3);
        }
    }
    atomicAdd(&s_nhi, my_hi);
    __syncthreads();

    const int nhi   = s_nhi;
    const int namb  = (s_namb < AMB_CAP) ? s_namb : AMB_CAP;
    const int kneed = Ksel - nhi;
    const bool fallback = (s_namb > AMB_CAP) || (kneed < 0) || (kneed > s_namb);

    if (fallback) {
        #pragma unroll
        for (int p = 0; p < 4; ++p) {
            float4 o;
            o.x = (v[p*4+0] >= thr) ? v[p*4+0] : 0.f;
            o.y = (v[p*4+1] >= thr) ? v[p*4+1] : 0.f;
            o.z = (v[p*4+2] >= thr) ? v[p*4+2] : 0.f;
            o.w = (v[p*4+3] >= thr) ? v[p*4+3] : 0.f;
            *(float4*)&rowp[(tx + 256 * p) << 2] = o;
        }
        return;
    }

    if (namb > kneed) {
        for (int j = 0; j < namb; ++j) {
            const int n = amb_idx[j];
            double partial = 0.0;
            for (int p = 0; p < Kdim / 256; ++p) {
                int k = tx + 256 * p;
                partial += ((double)x[(size_t)row * Kdim + k] - (double)pb[k]) *
                           (double)W[(size_t)k * N + n];
            }
            #pragma unroll
            for (int off = 32; off > 0; off >>= 1) partial += __shfl_down(partial, off);
            if ((tx & 63) == 0) dred[tx >> 6] = partial;
            __syncthreads();
            if (tx == 0) amb_d[j] = dred[0] + dred[1] + dred[2] + dred[3] + (double)be[n];
            __syncthreads();
        }
        if (tx == 0) {
            for (int j = 0; j < namb; ++j) {
                int greater = 0;
                for (int l = 0; l < namb; ++l)
                    if (amb_d[l] > amb_d[j]) greater++;
                amb_keep[j] = (greater < kneed) ? 1 : 0;
            }
        }
        __syncthreads();
    } else {
        for (int j = tx; j < namb; j += 256) amb_keep[j] = 1;
        __syncthreads();
    }

    #pragma unroll
    for (int p = 0; p < 4; ++p) {
        float4 o;
        float* po = (float*)&o;
        #pragma unroll
        for (int r = 0; r < 4; ++r) {
            int gi = ((tx + 256 * p) << 2) + r;
            float val = v[p*4+r];
            float ov;
            if (val > thr + BAND) ov = val;
            else if (val < thr - BAND) ov = 0.f;
            else {
                int keep = 0;
                for (int j = 0; j < namb; ++j)
                    if (amb_idx[j] == gi) { keep = amb_keep[j]; break; }
                ov = keep ? val : 0.f;
            }
            po[r] = ov;
        }
        *(float4*)&rowp[(tx + 256 * p) << 2] = o;
    }
}

extern "C" void kernel_launch(void* const* d_in, const int* in_sizes, int n_in,
                              void* d_out, int out_size, void* d_ws, size_t ws_size,
                              hipStream_t stream) {
    const float* x  = (const float*)d_in[0];
    const float* pb = (const float*)d_in[1];
    const float* W  = (const float*)d_in[2];
    const float* be = (const float*)d_in[3];
    float* out = (float*)d_out;

    const int D = in_sizes[1];          // 4096
    const int N = in_sizes[3];          // 4096
    const int M = in_sizes[0] / D;      // 16384

    const size_t szW = (size_t)N * D;   // elements per W plane
    const size_t szX = (size_t)M * D;   // elements per X plane
    const size_t needW    = 2ull * szW * sizeof(unsigned short);            // 64 MB
    const size_t needFull = needW + 2ull * szX * sizeof(unsigned short);    // 332 MB

    const bool div256 = (M % 256 == 0) && (N % 256 == 0) && (D % 32 == 0);

    if (ws_size >= needFull && div256) {
        unsigned short* Wt_hi = (unsigned short*)d_ws;
        unsigned short* Wt_lo = Wt_hi + szW;
        unsigned short* Xhi   = Wt_lo + szW;
        unsigned short* Xlo   = Xhi + szX;
        split_transpose_W<<<dim3(N / 64, D / 64), 256, 0, stream>>>(W, Wt_hi, Wt_lo, N, D);
        {
            size_t total = szX;
            int blocks = (int)((total / 8 + 255) / 256);
            presplit_x<<<blocks, 256, 0, stream>>>(x, pb, Xhi, Xlo, D, total);
        }
        gemm_presplit_i<<<dim3(N / 256, M / 256), 512, 0, stream>>>(
            Xhi, Xlo, Wt_hi, Wt_lo, be, out, M, N, D);
    } else {
        unsigned short* Wt_hi = (unsigned short*)d_ws;
        unsigned short* Wt_lo = Wt_hi + szW;
        split_transpose_W<<<dim3(N / 64, D / 64), 256, 0, stream>>>(W, Wt_hi, Wt_lo, N, D);
        gemm_split_bf16<<<dim3(N / 128, M / 128), 256, 0, stream>>>(
            x, pb, Wt_hi, Wt_lo, be, out, M, N, D);
    }
    topk_mask_exact<<<M, 256, 0, stream>>>(x, pb, W, be, out, N, D, 128);
}